// Round 2
// baseline (2520.393 us; speedup 1.0000x reference)
//
#include <hip/hip_runtime.h>

// CfC fused scan, round 2: projection pipelined one step behind the recurrence.
// 16 blocks x 512 threads (8 waves). Per step: 2 barriers (was 3).
//   Phase A: reload ha=h_{t-1}; GEMM_h (2 split chains) -> z -> zbuf;
//            p1(h_{t-1}) via ha regs -> silu -> dbuf        [off critical path]
//   Phase B: GEMM_f -> blend -> h_t -> hbuf;
//            p2(hdn_{t-1}) -> out_{t-1}                     [off critical path]

#define T_   512
#define IND  64
#define LAT  256
#define BBD  128
#define OUTD 64
#define HLF  128

typedef _Float16 half8 __attribute__((ext_vector_type(8)));
typedef float    f32x4 __attribute__((ext_vector_type(4)));
typedef float    f4    __attribute__((ext_vector_type(4)));

#define MFMA16(a,b,c) __builtin_amdgcn_mfma_f32_16x16x32_f16((a),(b),(c),0,0,0)

__device__ __forceinline__ float ex2(float x)   { return __builtin_amdgcn_exp2f(x); }
__device__ __forceinline__ float rcpf_(float x) { return __builtin_amdgcn_rcpf(x); }

__global__ void __launch_bounds__(512, 2) cfc_fused(
    const float* __restrict__ x,
    const float* __restrict__ Wb,  const float* __restrict__ bb,
    const float* __restrict__ W1,  const float* __restrict__ b1,
    const float* __restrict__ W2,  const float* __restrict__ b2,
    const float* __restrict__ Wa,  const float* __restrict__ ba,
    const float* __restrict__ Wtb, const float* __restrict__ btb,
    const float* __restrict__ Wp1, const float* __restrict__ bp1,
    const float* __restrict__ Wp2, const float* __restrict__ bp2,
    float* __restrict__ out)
{
    const int tid  = threadIdx.x;
    const int wv   = tid >> 6;
    const int lane = tid & 63;
    const int l15  = lane & 15;
    const int lg   = lane >> 4;     // 0..3
    const int krow = lg << 3;       // k-base within a 32-chunk
    const int b0   = blockIdx.x << 4;

    __shared__ __align__(16) _Float16 hbuf[16*LAT];  // h_t   [16][256]
    __shared__ __align__(16) _Float16 zbuf[16*BBD];  // z_t   [16][128]
    __shared__ __align__(16) _Float16 dbuf[16*HLF];  // hdn_{t-1} [16][128]

    // ---------------- persistent weight fragments (loaded once) -------------
    half8 WbB[10];                       // [x|h] @ Wb : K=320, cols 16w..16w+16
    {
        const int col = (wv<<4) + l15;
        #pragma unroll
        for (int kk = 0; kk < 10; ++kk) {
            half8 v;
            #pragma unroll
            for (int e = 0; e < 8; ++e)
                v[e] = (_Float16)Wb[(kk*32 + krow + e)*BBD + col];
            WbB[kk] = v;
        }
    }
    half8 WfB[6][4];  // tiles: 0,1=W1  2,3=W2  4,5=Wa+Wtb ; 1.7159 folded in
    #pragma unroll
    for (int t6 = 0; t6 < 6; ++t6) {
        const int m   = t6 >> 1;
        const int col = (wv<<5) + ((t6&1)<<4) + l15;
        const float* Wm = (m==0) ? W1 : ((m==1) ? W2 : Wa);
        #pragma unroll
        for (int kk = 0; kk < 4; ++kk) {
            half8 v;
            #pragma unroll
            for (int e = 0; e < 8; ++e) {
                const int k = kk*32 + krow + e;
                float f = Wm[k*LAT + col];
                if (m == 2) f += Wtb[k*LAT + col];
                v[e] = (_Float16)(1.7159f * f);
            }
            WfB[t6][kk] = v;
        }
    }
    half8 Wp1B[8];                       // h @ Wp1 : K=256, cols 16w..16w+16
    {
        const int col = (wv<<4) + l15;
        #pragma unroll
        for (int kk = 0; kk < 8; ++kk) {
            half8 v;
            #pragma unroll
            for (int e = 0; e < 8; ++e)
                v[e] = (_Float16)Wp1[(kk*32 + krow + e)*HLF + col];
            Wp1B[kk] = v;
        }
    }
    half8 Wp2B[4];                       // hdn @ Wp2 : K=128, waves 0..3 only
    if (wv < 4) {
        const int col = (wv<<4) + l15;
        #pragma unroll
        for (int kk = 0; kk < 4; ++kk) {
            half8 v;
            #pragma unroll
            for (int e = 0; e < 8; ++e)
                v[e] = (_Float16)Wp2[(kk*32 + krow + e)*OUTD + col];
            Wp2B[kk] = v;
        }
    }

    // ---------------- per-lane bias constants (pre-scaled) ------------------
    const float K1 = 1.4426950408889634f;   // log2(e)
    const float K2 = 2.8853900817779268f;   // 2*log2(e)
    const float KZ = 1.9216698144680396f;   // 1.332*log2(e)
    const int cz  = (wv<<4) + l15;          // 0..127
    const int cf0 = (wv<<5) + l15;          // 0..255 (sub 0)
    const int cf1 = cf0 + 16;               // sub 1
    const float bbr   = bb[cz] * KZ;
    const float b1r0  = b1[cf0]*K2,  b1r1  = b1[cf1]*K2;
    const float b2r0  = b2[cf0]*K2,  b2r1  = b2[cf1]*K2;
    const float batr0 = (ba[cf0]+btb[cf0])*K1, batr1 = (ba[cf1]+btb[cf1])*K1;
    const float bp1a  = bp1[cz];
    const float bp1k  = bp1a * K1;
    const float bp2r  = (wv < 4) ? bp2[cz] : 0.f;

    // x prefetch (A-frag rows are batch rows = l15; 8 contiguous floats per kk)
    const float* xrow = x + (size_t)(b0 + l15) * (T_*IND);
    f4 xq[4];
    #pragma unroll
    for (int q = 0; q < 4; ++q)
        xq[q] = *(const f4*)(xrow + ((q>>1)*32 + krow + (q&1)*4));

    half8 ha[8];                            // h_{t-1} A-fragments (h0 = 0)
    {
        half8 hz;
        #pragma unroll
        for (int e = 0; e < 8; ++e) hz[e] = (_Float16)0.f;
        #pragma unroll
        for (int i = 0; i < 8; ++i) ha[i] = hz;
    }
    const f32x4 fz = {0.f, 0.f, 0.f, 0.f};
    float* const obase = out + (size_t)(b0 + (lg<<2)) * (T_*OUTD) + (wv<<4) + l15;

    #pragma unroll 1
    for (int t = 0; t < T_; ++t) {
        // ============================ PHASE A ============================
        // reload h_{t-1} A-frags (written to hbuf in phase B of t-1)
        if (t > 0) {
            #pragma unroll
            for (int kk = 0; kk < 8; ++kk)
                ha[kk] = *(const half8*)&hbuf[(l15*LAT + kk*32 + krow) ^ ((l15&7)<<3)];
        }

        // convert this step's x, then prefetch next step's
        half8 xa0, xa1;
        #pragma unroll
        for (int e = 0; e < 4; ++e) {
            xa0[e]   = (_Float16)xq[0][e];
            xa0[e+4] = (_Float16)xq[1][e];
            xa1[e]   = (_Float16)xq[2][e];
            xa1[e+4] = (_Float16)xq[3][e];
        }
        {
            const int tn = (t < T_-1) ? (t+1) : t;
            const float* p = xrow + tn*IND + krow;
            #pragma unroll
            for (int q = 0; q < 4; ++q)
                xq[q] = *(const f4*)(p + (q>>1)*32 + (q&1)*4);
        }

        // GEMM_h: preZ = [x_t | h_{t-1}] @ Wb   -- two parallel chains
        f32x4 az0 = MFMA16(xa0, WbB[0], fz);
        f32x4 az1 = MFMA16(xa1, WbB[1], fz);
        #pragma unroll
        for (int kk = 0; kk < 8; kk += 2) {
            az0 = MFMA16(ha[kk],   WbB[kk+2], az0);
            az1 = MFMA16(ha[kk+1], WbB[kk+3], az1);
        }
        const f32x4 az = az0 + az1;

        // z = tanh(0.666*(preZ+bb))    (1.7159 folded into WfB)
        #pragma unroll
        for (int r = 0; r < 4; ++r) {
            const float E = ex2(__builtin_fmaf(az[r], KZ, bbr));
            const float z = __builtin_fmaf(-2.f, rcpf_(E + 1.f), 1.f);
            const int row = (lg<<2) + r;
            zbuf[(row*BBD + cz) ^ ((row&7)<<3)] = (_Float16)z;
        }

        // p1 for step t-1 (reuses ha = h_{t-1}; off the critical path)
        if (t > 0) {
            f32x4 ap0 = fz, ap1 = fz;
            #pragma unroll
            for (int kk = 0; kk < 8; kk += 2) {
                ap0 = MFMA16(ha[kk],   Wp1B[kk],   ap0);
                ap1 = MFMA16(ha[kk+1], Wp1B[kk+1], ap1);
            }
            const f32x4 ap = ap0 + ap1;
            #pragma unroll
            for (int r = 0; r < 4; ++r) {
                const float v  = ap[r] + bp1a;
                const float E  = ex2(__builtin_fmaf(ap[r], K1, bp1k));  // e^v
                const float sg = rcpf_(E + 1.f);                        // 1-sigmoid(v)
                const float hd = __builtin_fmaf(-v, sg, v);             // v*sigmoid(v)
                const int row = (lg<<2) + r;
                dbuf[(row*HLF + cz) ^ ((row&7)<<3)] = (_Float16)hd;
            }
        }
        __syncthreads();   // barrier 1: zbuf/dbuf ready

        // ============================ PHASE B ============================
        // GEMM_f: z @ [W1|W2|Wat]
        half8 za[4];
        #pragma unroll
        for (int kk = 0; kk < 4; ++kk)
            za[kk] = *(const half8*)&zbuf[(l15*BBD + kk*32 + krow) ^ ((l15&7)<<3)];
        f32x4 af[6];
        #pragma unroll
        for (int i = 0; i < 6; ++i) af[i] = fz;
        #pragma unroll
        for (int kk = 0; kk < 4; ++kk) {
            #pragma unroll
            for (int i = 0; i < 6; ++i) af[i] = MFMA16(za[kk], WfB[i][kk], af[i]);
        }

        // blend h = 1 - 2*[(1+E2) + E3*(1+E1)] / [(1+E1)(1+E2)(1+E3)]
        #pragma unroll
        for (int sub = 0; sub < 2; ++sub) {
            const float b1r  = sub ? b1r1  : b1r0;
            const float b2r  = sub ? b2r1  : b2r0;
            const float batr = sub ? batr1 : batr0;
            #pragma unroll
            for (int r = 0; r < 4; ++r) {
                const float E1 = ex2(__builtin_fmaf(af[0+sub][r], K2, b1r));
                const float E2 = ex2(__builtin_fmaf(af[2+sub][r], K2, b2r));
                const float E3 = ex2(__builtin_fmaf(af[4+sub][r], K1, batr));
                const float p1_ = E1 + 1.f;
                const float p2_ = E2 + 1.f;
                const float p3_ = E3 + 1.f;
                const float num = __builtin_fmaf(E3, p1_, p2_);
                const float hv  = __builtin_fmaf(-2.f*num, rcpf_(p1_*p2_*p3_), 1.f);
                const int row = (lg<<2) + r;
                hbuf[(row*LAT + (wv<<5) + (sub<<4) + l15) ^ ((row&7)<<3)] = (_Float16)hv;
            }
        }

        // p2 for step t-1: out_{t-1} = hdn_{t-1} @ Wp2 + bp2 (waves 0..3)
        if (t > 0 && wv < 4) {
            f32x4 ao = fz;
            #pragma unroll
            for (int kk = 0; kk < 4; ++kk) {
                const half8 aa = *(const half8*)&dbuf[(l15*HLF + kk*32 + krow) ^ ((l15&7)<<3)];
                ao = MFMA16(aa, Wp2B[kk], ao);
            }
            #pragma unroll
            for (int r = 0; r < 4; ++r)
                obase[(size_t)r*(T_*OUTD) + (size_t)(t-1)*OUTD] = ao[r] + bp2r;
        }
        __syncthreads();   // barrier 2: hbuf ready for t+1; dbuf free
    }

    // ===================== epilogue: project h_{511} =====================
    {
        #pragma unroll
        for (int kk = 0; kk < 8; ++kk)
            ha[kk] = *(const half8*)&hbuf[(l15*LAT + kk*32 + krow) ^ ((l15&7)<<3)];
        f32x4 ap0 = fz, ap1 = fz;
        #pragma unroll
        for (int kk = 0; kk < 8; kk += 2) {
            ap0 = MFMA16(ha[kk],   Wp1B[kk],   ap0);
            ap1 = MFMA16(ha[kk+1], Wp1B[kk+1], ap1);
        }
        const f32x4 ap = ap0 + ap1;
        #pragma unroll
        for (int r = 0; r < 4; ++r) {
            const float v  = ap[r] + bp1a;
            const float E  = ex2(__builtin_fmaf(ap[r], K1, bp1k));
            const float sg = rcpf_(E + 1.f);
            const float hd = __builtin_fmaf(-v, sg, v);
            const int row = (lg<<2) + r;
            dbuf[(row*HLF + cz) ^ ((row&7)<<3)] = (_Float16)hd;
        }
        __syncthreads();
        if (wv < 4) {
            f32x4 ao = fz;
            #pragma unroll
            for (int kk = 0; kk < 4; ++kk) {
                const half8 aa = *(const half8*)&dbuf[(l15*HLF + kk*32 + krow) ^ ((l15&7)<<3)];
                ao = MFMA16(aa, Wp2B[kk], ao);
            }
            #pragma unroll
            for (int r = 0; r < 4; ++r)
                obase[(size_t)r*(T_*OUTD) + (size_t)(T_-1)*OUTD] = ao[r] + bp2r;
        }
    }
}

extern "C" void kernel_launch(void* const* d_in, const int* in_sizes, int n_in,
                              void* d_out, int out_size, void* d_ws, size_t ws_size,
                              hipStream_t stream) {
    (void)in_sizes; (void)n_in; (void)out_size; (void)d_ws; (void)ws_size;
    const float* x   = (const float*)d_in[0];
    const float* Wb  = (const float*)d_in[1];
    const float* bb  = (const float*)d_in[2];
    const float* W1  = (const float*)d_in[3];
    const float* b1  = (const float*)d_in[4];
    const float* W2  = (const float*)d_in[5];
    const float* b2  = (const float*)d_in[6];
    const float* Wa  = (const float*)d_in[7];
    const float* ba  = (const float*)d_in[8];
    const float* Wtb = (const float*)d_in[9];
    const float* btb = (const float*)d_in[10];
    const float* Wp1 = (const float*)d_in[11];
    const float* bp1 = (const float*)d_in[12];
    const float* Wp2 = (const float*)d_in[13];
    const float* bp2 = (const float*)d_in[14];
    cfc_fused<<<dim3(16), dim3(512), 0, stream>>>(
        x, Wb, bb, W1, b1, W2, b2, Wa, ba, Wtb, btb, Wp1, bp1, Wp2, bp2,
        (float*)d_out);
}

// Round 3
// 1345.265 us; speedup vs baseline: 1.8735x; 1.8735x over previous
//
#include <hip/hip_runtime.h>

// CfC fused scan, round 3: fit the register budget (kill spills).
// 16 blocks x 512 threads (8 waves). 2 barriers/step, projection pipelined
// one step behind (R2 structure). NEW: Wp1/Wp2 B-fragments live in LDS
// (packed once in prologue), not registers -> ~220 live regs < 256 budget.
//   Phase A: reload ha=h_{t-1}; GEMM_h -> z -> zbuf;
//            p1(h_{t-1}) via ha regs + Wp1-from-LDS -> silu -> dbuf
//   Phase B: GEMM_f -> blend -> h_t -> hbuf;
//            p2(hdn_{t-1}) via Wp2-from-LDS -> out_{t-1}

#define T_   512
#define IND  64
#define LAT  256
#define BBD  128
#define OUTD 64
#define HLF  128

typedef _Float16 half8 __attribute__((ext_vector_type(8)));
typedef float    f32x4 __attribute__((ext_vector_type(4)));
typedef float    f4    __attribute__((ext_vector_type(4)));

#define MFMA16(a,b,c) __builtin_amdgcn_mfma_f32_16x16x32_f16((a),(b),(c),0,0,0)

__device__ __forceinline__ float ex2(float x)   { return __builtin_amdgcn_exp2f(x); }
__device__ __forceinline__ float rcpf_(float x) { return __builtin_amdgcn_rcpf(x); }

__global__ void __launch_bounds__(512, 2) cfc_fused(
    const float* __restrict__ x,
    const float* __restrict__ Wb,  const float* __restrict__ bb,
    const float* __restrict__ W1,  const float* __restrict__ b1,
    const float* __restrict__ W2,  const float* __restrict__ b2,
    const float* __restrict__ Wa,  const float* __restrict__ ba,
    const float* __restrict__ Wtb, const float* __restrict__ btb,
    const float* __restrict__ Wp1, const float* __restrict__ bp1,
    const float* __restrict__ Wp2, const float* __restrict__ bp2,
    float* __restrict__ out)
{
    const int tid  = threadIdx.x;
    const int wv   = tid >> 6;
    const int lane = tid & 63;
    const int l15  = lane & 15;
    const int lg   = lane >> 4;     // 0..3
    const int krow = lg << 3;       // k-base within a 32-chunk
    const int b0   = blockIdx.x << 4;

    __shared__ __align__(16) _Float16 hbuf[16*LAT];   // h_t       [16][256]  8KB
    __shared__ __align__(16) _Float16 zbuf[16*BBD];   // z_t       [16][128]  4KB
    __shared__ __align__(16) _Float16 dbuf[16*HLF];   // hdn_{t-1} [16][128]  4KB
    __shared__ __align__(16) _Float16 wp1l[8*8*64*8]; // Wp1 B-frags         64KB
    __shared__ __align__(16) _Float16 wp2l[4*4*64*8]; // Wp2 B-frags         16KB

    // ------- persistent recurrence weight fragments (registers, 136) -------
    half8 WbB[10];                       // [x|h] @ Wb : K=320, cols 16w..16w+16
    {
        const int col = (wv<<4) + l15;
        #pragma unroll
        for (int kk = 0; kk < 10; ++kk) {
            half8 v;
            #pragma unroll
            for (int e = 0; e < 8; ++e)
                v[e] = (_Float16)Wb[(kk*32 + krow + e)*BBD + col];
            WbB[kk] = v;
        }
    }
    half8 WfB[6][4];  // tiles: 0,1=W1  2,3=W2  4,5=Wa+Wtb ; 1.7159 folded in
    #pragma unroll
    for (int t6 = 0; t6 < 6; ++t6) {
        const int m   = t6 >> 1;
        const int col = (wv<<5) + ((t6&1)<<4) + l15;
        const float* Wm = (m==0) ? W1 : ((m==1) ? W2 : Wa);
        #pragma unroll
        for (int kk = 0; kk < 4; ++kk) {
            half8 v;
            #pragma unroll
            for (int e = 0; e < 8; ++e) {
                const int k = kk*32 + krow + e;
                float f = Wm[k*LAT + col];
                if (m == 2) f += Wtb[k*LAT + col];
                v[e] = (_Float16)(1.7159f * f);
            }
            WfB[t6][kk] = v;
        }
    }

    // ------- projection weights -> LDS, packed in B-fragment order ---------
    {
        const int col = (wv<<4) + l15;
        #pragma unroll
        for (int kk = 0; kk < 8; ++kk) {
            half8 v;
            #pragma unroll
            for (int e = 0; e < 8; ++e)
                v[e] = (_Float16)Wp1[(kk*32 + krow + e)*HLF + col];
            *(half8*)&wp1l[((wv<<3) + kk)*512 + (lane<<3)] = v;
        }
        if (wv < 4) {
            #pragma unroll
            for (int kk = 0; kk < 4; ++kk) {
                half8 v;
                #pragma unroll
                for (int e = 0; e < 8; ++e)
                    v[e] = (_Float16)Wp2[(kk*32 + krow + e)*OUTD + col];
                *(half8*)&wp2l[((wv<<2) + kk)*512 + (lane<<3)] = v;
            }
        }
    }
    const _Float16* const wp1p = &wp1l[(wv<<3)*512 + (lane<<3)];
    const _Float16* const wp2p = &wp2l[(wv<<2)*512 + (lane<<3)];

    // ---------------- per-lane bias constants (pre-scaled) ------------------
    const float K1 = 1.4426950408889634f;   // log2(e)
    const float K2 = 2.8853900817779268f;   // 2*log2(e)
    const float KZ = 1.9216698144680396f;   // 1.332*log2(e)
    const int cz  = (wv<<4) + l15;          // 0..127
    const int cf0 = (wv<<5) + l15;          // 0..255 (sub 0)
    const int cf1 = cf0 + 16;               // sub 1
    const float bbr   = bb[cz] * KZ;
    const float b1r0  = b1[cf0]*K2,  b1r1  = b1[cf1]*K2;
    const float b2r0  = b2[cf0]*K2,  b2r1  = b2[cf1]*K2;
    const float batr0 = (ba[cf0]+btb[cf0])*K1, batr1 = (ba[cf1]+btb[cf1])*K1;
    const float bp1a  = bp1[cz];
    const float bp1k  = bp1a * K1;
    const float bp2r  = (wv < 4) ? bp2[cz] : 0.f;

    __syncthreads();   // wp1l/wp2l visible to all waves

    // x prefetch (A-frag rows are batch rows = l15; 8 contiguous floats per kk)
    const float* xrow = x + (size_t)(b0 + l15) * (T_*IND);
    f4 xq[4];
    #pragma unroll
    for (int q = 0; q < 4; ++q)
        xq[q] = *(const f4*)(xrow + ((q>>1)*32 + krow + (q&1)*4));

    half8 ha[8];                            // h_{t-1} A-fragments (h0 = 0)
    {
        half8 hz;
        #pragma unroll
        for (int e = 0; e < 8; ++e) hz[e] = (_Float16)0.f;
        #pragma unroll
        for (int i = 0; i < 8; ++i) ha[i] = hz;
    }
    const f32x4 fz = {0.f, 0.f, 0.f, 0.f};
    float* const obase = out + (size_t)(b0 + (lg<<2)) * (T_*OUTD) + (wv<<4) + l15;

    #pragma unroll 1
    for (int t = 0; t < T_; ++t) {
        // ============================ PHASE A ============================
        // reload h_{t-1} A-frags (written to hbuf in phase B of t-1)
        if (t > 0) {
            #pragma unroll
            for (int kk = 0; kk < 8; ++kk)
                ha[kk] = *(const half8*)&hbuf[(l15*LAT + kk*32 + krow) ^ ((l15&7)<<3)];
        }

        // convert this step's x, then prefetch next step's
        half8 xa0, xa1;
        #pragma unroll
        for (int e = 0; e < 4; ++e) {
            xa0[e]   = (_Float16)xq[0][e];
            xa0[e+4] = (_Float16)xq[1][e];
            xa1[e]   = (_Float16)xq[2][e];
            xa1[e+4] = (_Float16)xq[3][e];
        }
        {
            const int tn = (t < T_-1) ? (t+1) : t;
            const float* p = xrow + tn*IND + krow;
            #pragma unroll
            for (int q = 0; q < 4; ++q)
                xq[q] = *(const f4*)(p + (q>>1)*32 + (q&1)*4);
        }

        // GEMM_h: preZ = [x_t | h_{t-1}] @ Wb   -- two parallel chains
        f32x4 az0 = MFMA16(xa0, WbB[0], fz);
        f32x4 az1 = MFMA16(xa1, WbB[1], fz);
        #pragma unroll
        for (int kk = 0; kk < 8; kk += 2) {
            az0 = MFMA16(ha[kk],   WbB[kk+2], az0);
            az1 = MFMA16(ha[kk+1], WbB[kk+3], az1);
        }
        const f32x4 az = az0 + az1;

        // z = tanh(0.666*(preZ+bb))    (1.7159 folded into WfB)
        #pragma unroll
        for (int r = 0; r < 4; ++r) {
            const float E = ex2(__builtin_fmaf(az[r], KZ, bbr));
            const float z = __builtin_fmaf(-2.f, rcpf_(E + 1.f), 1.f);
            const int row = (lg<<2) + r;
            zbuf[(row*BBD + cz) ^ ((row&7)<<3)] = (_Float16)z;
        }

        // p1 for step t-1 (reuses ha = h_{t-1}; Wp1 frags from LDS)
        if (t > 0) {
            f32x4 ap0 = fz, ap1 = fz;
            #pragma unroll
            for (int kk = 0; kk < 8; kk += 2) {
                ap0 = MFMA16(ha[kk],   *(const half8*)(wp1p +  kk   *512), ap0);
                ap1 = MFMA16(ha[kk+1], *(const half8*)(wp1p + (kk+1)*512), ap1);
            }
            const f32x4 ap = ap0 + ap1;
            #pragma unroll
            for (int r = 0; r < 4; ++r) {
                const float v  = ap[r] + bp1a;
                const float E  = ex2(__builtin_fmaf(ap[r], K1, bp1k));  // e^v
                const float sg = rcpf_(E + 1.f);                        // 1-sigmoid(v)
                const float hd = __builtin_fmaf(-v, sg, v);             // v*sigmoid(v)
                const int row = (lg<<2) + r;
                dbuf[(row*HLF + cz) ^ ((row&7)<<3)] = (_Float16)hd;
            }
        }
        __syncthreads();   // barrier 1: zbuf/dbuf ready

        // ============================ PHASE B ============================
        // GEMM_f: z @ [W1|W2|Wat]
        half8 za[4];
        #pragma unroll
        for (int kk = 0; kk < 4; ++kk)
            za[kk] = *(const half8*)&zbuf[(l15*BBD + kk*32 + krow) ^ ((l15&7)<<3)];
        f32x4 af[6];
        #pragma unroll
        for (int i = 0; i < 6; ++i) af[i] = fz;
        #pragma unroll
        for (int kk = 0; kk < 4; ++kk) {
            #pragma unroll
            for (int i = 0; i < 6; ++i) af[i] = MFMA16(za[kk], WfB[i][kk], af[i]);
        }

        // blend h = 1 - 2*[(1+E2) + E3*(1+E1)] / [(1+E1)(1+E2)(1+E3)]
        #pragma unroll
        for (int sub = 0; sub < 2; ++sub) {
            const float b1r  = sub ? b1r1  : b1r0;
            const float b2r  = sub ? b2r1  : b2r0;
            const float batr = sub ? batr1 : batr0;
            #pragma unroll
            for (int r = 0; r < 4; ++r) {
                const float E1 = ex2(__builtin_fmaf(af[0+sub][r], K2, b1r));
                const float E2 = ex2(__builtin_fmaf(af[2+sub][r], K2, b2r));
                const float E3 = ex2(__builtin_fmaf(af[4+sub][r], K1, batr));
                const float p1_ = E1 + 1.f;
                const float p2_ = E2 + 1.f;
                const float p3_ = E3 + 1.f;
                const float num = __builtin_fmaf(E3, p1_, p2_);
                const float hv  = __builtin_fmaf(-2.f*num, rcpf_(p1_*p2_*p3_), 1.f);
                const int row = (lg<<2) + r;
                hbuf[(row*LAT + (wv<<5) + (sub<<4) + l15) ^ ((row&7)<<3)] = (_Float16)hv;
            }
        }

        // p2 for step t-1: out_{t-1} = hdn_{t-1} @ Wp2 + bp2 (waves 0..3)
        if (t > 0 && wv < 4) {
            f32x4 ao = fz;
            #pragma unroll
            for (int kk = 0; kk < 4; ++kk) {
                const half8 aa = *(const half8*)&dbuf[(l15*HLF + kk*32 + krow) ^ ((l15&7)<<3)];
                ao = MFMA16(aa, *(const half8*)(wp2p + kk*512), ao);
            }
            #pragma unroll
            for (int r = 0; r < 4; ++r)
                obase[(size_t)r*(T_*OUTD) + (size_t)(t-1)*OUTD] = ao[r] + bp2r;
        }
        __syncthreads();   // barrier 2: hbuf ready for t+1; dbuf free
    }

    // ===================== epilogue: project h_{511} =====================
    {
        #pragma unroll
        for (int kk = 0; kk < 8; ++kk)
            ha[kk] = *(const half8*)&hbuf[(l15*LAT + kk*32 + krow) ^ ((l15&7)<<3)];
        f32x4 ap0 = fz, ap1 = fz;
        #pragma unroll
        for (int kk = 0; kk < 8; kk += 2) {
            ap0 = MFMA16(ha[kk],   *(const half8*)(wp1p +  kk   *512), ap0);
            ap1 = MFMA16(ha[kk+1], *(const half8*)(wp1p + (kk+1)*512), ap1);
        }
        const f32x4 ap = ap0 + ap1;
        #pragma unroll
        for (int r = 0; r < 4; ++r) {
            const float v  = ap[r] + bp1a;
            const float E  = ex2(__builtin_fmaf(ap[r], K1, bp1k));
            const float sg = rcpf_(E + 1.f);
            const float hd = __builtin_fmaf(-v, sg, v);
            const int row = (lg<<2) + r;
            dbuf[(row*HLF + cz) ^ ((row&7)<<3)] = (_Float16)hd;
        }
        __syncthreads();
        if (wv < 4) {
            f32x4 ao = fz;
            #pragma unroll
            for (int kk = 0; kk < 4; ++kk) {
                const half8 aa = *(const half8*)&dbuf[(l15*HLF + kk*32 + krow) ^ ((l15&7)<<3)];
                ao = MFMA16(aa, *(const half8*)(wp2p + kk*512), ao);
            }
            #pragma unroll
            for (int r = 0; r < 4; ++r)
                obase[(size_t)r*(T_*OUTD) + (size_t)(T_-1)*OUTD] = ao[r] + bp2r;
        }
    }
}

extern "C" void kernel_launch(void* const* d_in, const int* in_sizes, int n_in,
                              void* d_out, int out_size, void* d_ws, size_t ws_size,
                              hipStream_t stream) {
    (void)in_sizes; (void)n_in; (void)out_size; (void)d_ws; (void)ws_size;
    const float* x   = (const float*)d_in[0];
    const float* Wb  = (const float*)d_in[1];
    const float* bb  = (const float*)d_in[2];
    const float* W1  = (const float*)d_in[3];
    const float* b1  = (const float*)d_in[4];
    const float* W2  = (const float*)d_in[5];
    const float* b2  = (const float*)d_in[6];
    const float* Wa  = (const float*)d_in[7];
    const float* ba  = (const float*)d_in[8];
    const float* Wtb = (const float*)d_in[9];
    const float* btb = (const float*)d_in[10];
    const float* Wp1 = (const float*)d_in[11];
    const float* bp1 = (const float*)d_in[12];
    const float* Wp2 = (const float*)d_in[13];
    const float* bp2 = (const float*)d_in[14];
    cfc_fused<<<dim3(16), dim3(512), 0, stream>>>(
        x, Wb, bb, W1, b1, W2, b2, Wa, ba, Wtb, btb, Wp1, bp1, Wp2, bp2,
        (float*)d_out);
}